// Round 15
// baseline (94.432 us; speedup 1.0000x reference)
//
#include <hip/hip_runtime.h>
#include <math.h>

#define NP 16384
#define NG 2048
#define NC 17

#define GRIDSZ 0.4f
#define PCMINX -40.0f
#define PCMINY -40.0f
#define PCMINZ -1.0f
#define SCALE_MULTC 3.0f

// Heavy superquadric evaluation for one primitive g (lane-divergent, rare).
__device__ __forceinline__ float eval_prim(const float* __restrict__ means3D,
                                           const float* __restrict__ opas,
                                           const float* __restrict__ uu,
                                           const float* __restrict__ vv,
                                           const float* __restrict__ scales,
                                           const float* __restrict__ rot3D,
                                           int g, float px, float py, float pz) {
    const float* r = rot3D + (size_t)g * 9;
    float dx = px - means3D[g * 3 + 0];
    float dy = py - means3D[g * 3 + 1];
    float dz = pz - means3D[g * 3 + 2];
    float l0 = dx * r[0] + dy * r[3] + dz * r[6];
    float l1 = dx * r[1] + dy * r[4] + dz * r[7];
    float l2 = dx * r[2] + dy * r[5] + dz * r[8];
    float t0 = l0 / scales[g * 3 + 0];
    float t1 = l1 / scales[g * 3 + 1];
    float t2 = l2 / scales[g * 3 + 2];
    float s0 = t0 * t0 + 1e-8f;
    float s1 = t1 * t1 + 1e-8f;
    float s2 = t2 * t2 + 1e-8f;
    float ie1 = 1.0f / uu[g];
    float ie2 = 1.0f / vv[g];
    float e21 = vv[g] * ie1;
    float f = __powf(__powf(s0, ie2) + __powf(s1, ie2), e21) + __powf(s2, ie1);
    return opas[g] * __expf(-0.5f * f);
}

// ONE dispatch, no workspace. 2048 blocks x 512 threads (8 waves = 8 points).
// Phase 1: block builds packed AABB table in LDS (u32 per prim:
// vx | vy<<8 | vz<<16 | rad<<24; vx,vy<200, vz<16, rad<=5 all fit).
// Phase 2: wave = one point; lane k tests prim i*64+k (32 iterations,
// ~16 VALU + 1 bank-clean ds_read_b32 each). Heavy path only when the wave
// ballot is nonzero (~1.3 iterations per wave): inline eval + per-hit shfl
// broadcast; density/logbin accumulated identically on all lanes (uniform),
// semantics fmaf on lanes<17. Deterministic: fixed i/lane order, no atomics.
__global__ __launch_bounds__(512)
void fused_kernel(const float* __restrict__ pts,
                  const float* __restrict__ means3D,
                  const float* __restrict__ opas,
                  const float* __restrict__ uu,
                  const float* __restrict__ vv,
                  const float* __restrict__ semantics,
                  const float* __restrict__ scales,
                  const float* __restrict__ rot3D,
                  float* __restrict__ out) {
    __shared__ unsigned aab[NG];   // 8 KB
    const int tid = threadIdx.x;
    const int lane = tid & 63;
    const int w = tid >> 6;

    // ---- Phase 1: packed AABB table ----
#pragma unroll
    for (int it = 0; it < NG / 512; ++it) {
        int g = it * 512 + tid;
        float mx = means3D[g * 3 + 0], my = means3D[g * 3 + 1], mz = means3D[g * 3 + 2];
        float sx = scales[g * 3 + 0], sy = scales[g * 3 + 1], sz = scales[g * 3 + 2];
        int vx = (int)floorf((mx - PCMINX) / GRIDSZ);
        int vy = (int)floorf((my - PCMINY) / GRIDSZ);
        int vz = (int)floorf((mz - PCMINZ) / GRIDSZ);
        float smax = fmaxf(sx, fmaxf(sy, sz));
        int rad = (int)ceilf(smax * SCALE_MULTC / GRIDSZ);
        if (rad < 1) rad = 1;
        aab[g] = (unsigned)vx | ((unsigned)vy << 8) | ((unsigned)vz << 16) |
                 ((unsigned)rad << 24);
    }
    __syncthreads();

    // ---- Phase 2: wave = point ----
    const int p = blockIdx.x * 8 + w;
    const float px = pts[p * 3 + 0], py = pts[p * 3 + 1], pz = pts[p * 3 + 2];
    const int ix = (int)floorf((px - PCMINX) / GRIDSZ);
    const int iy = (int)floorf((py - PCMINY) / GRIDSZ);
    const int iz = (int)floorf((pz - PCMINZ) / GRIDSZ);

    float dens = 0.0f, lb = 0.0f, acc = 0.0f;

#pragma unroll 4
    for (int i = 0; i < NG / 64; ++i) {
        unsigned wv = aab[i * 64 + lane];   // bank-clean (2-way, free)
        int cheb = max(max(abs(ix - (int)(wv & 0xffu)),
                           abs(iy - (int)((wv >> 8) & 0xffu))),
                       abs(iz - (int)((wv >> 16) & 0xffu)));
        bool hit = cheb <= (int)(wv >> 24);
        unsigned long long bal = __ballot(hit);
        if (bal) {   // wave-uniform branch, rare (~1.3 of 32 iterations)
            float a = 0.0f;
            if (hit)
                a = eval_prim(means3D, opas, uu, vv, scales, rot3D,
                              i * 64 + lane, px, py, pz);
            while (bal) {
                int l = __builtin_ctzll(bal);
                bal &= bal - 1;
                float ak = __shfl(a, l);
                int gk = i * 64 + l;
                dens += ak;                                    // uniform on all lanes
                lb += __logf(1.0f - fminf(ak, 1.0f - 1e-4f));  // uniform on all lanes
                if (lane < NC)
                    acc = fmaf(ak, semantics[(size_t)gk * NC + lane], acc);
            }
        }
    }

    float inv = 1.0f / (dens + 1e-9f);
    if (lane < NC) out[(size_t)p * NC + lane] = acc * inv;
    if (lane == 0) {
        out[(size_t)NP * NC + p] = 1.0f - expf(lb);
        out[(size_t)NP * NC + NP + p] = dens;
    }
}

extern "C" void kernel_launch(void* const* d_in, const int* in_sizes, int n_in,
                              void* d_out, int out_size, void* d_ws, size_t ws_size,
                              hipStream_t stream) {
    const float* pts       = (const float*)d_in[0];
    const float* means3D   = (const float*)d_in[1];
    const float* opas      = (const float*)d_in[2];
    const float* uu        = (const float*)d_in[3];
    const float* vv        = (const float*)d_in[4];
    const float* semantics = (const float*)d_in[5];
    const float* scales    = (const float*)d_in[6];
    const float* rot3D     = (const float*)d_in[7];
    float* out = (float*)d_out;

    fused_kernel<<<NP / 8, 512, 0, stream>>>(pts, means3D, opas, uu, vv, semantics,
                                             scales, rot3D, out);
}

// Round 16
// 29.326 us; speedup vs baseline: 3.2201x; 3.2201x over previous
//
#include <hip/hip_runtime.h>
#include <math.h>

#define NP 16384
#define NG 2048
#define NC 17

#define TSH 3            // tile = 8x8 voxels in (x,y)
#define NTX 25
#define NTY 25
#define NTILE (NTX * NTY)   // 625
#define SEGC 32          // per-wave candidate cap in bin (4 ranges of 512 prims)
#define CCAP 128         // per-tile candidate cap (mean ~13)
#define ROWF 40          // floats per candidate row

#define GRIDSZ 0.4f
#define PCMINX -40.0f
#define PCMINY -40.0f
#define PCMINZ -1.0f
#define SCALE_MULTC 3.0f

// Row layout (40 floats, 10 float4s):
// f0={mur0,mur1,mur2,r0} f1={r1,r2,r3,r4} f2={r5,r6,r7,r8}
// f3={1/sx,1/sy,1/sz,opa} f4={1/u,1/v,v/u,sem16} f5..f8=sem[0..15]
// f9={vx,vy,vz,rad} (ints bitcast)
// Channel c<16 lives at float 20+c; channel 16 at float 19.

// Dispatch 1 (r13 verbatim): one block per tile; ballot-compact overlapping
// prims (ascending g, deterministic, no atomics, no memset); thread i builds
// candidate row i in the ws row table.
__global__ __launch_bounds__(256)
void bin_kernel(const float* __restrict__ means3D, const float* __restrict__ opas,
                const float* __restrict__ uu, const float* __restrict__ vv,
                const float* __restrict__ semantics, const float* __restrict__ scales,
                const float* __restrict__ rot3D,
                unsigned int* __restrict__ candCnt, float* __restrict__ rowTbl) {
    __shared__ unsigned short candSeg[4][SEGC];
    __shared__ int wc[4];
    const int tid = threadIdx.x;
    const int lane = tid & 63;
    const int w = tid >> 6;
    const int b = blockIdx.x;
    const int tx = b % NTX, ty = b / NTX;

    unsigned cl = 0;
#pragma unroll
    for (int it = 0; it < 8; ++it) {
        int g = w * 512 + it * 64 + lane;
        float mx = means3D[g * 3 + 0], my = means3D[g * 3 + 1];
        float sx = scales[g * 3 + 0], sy = scales[g * 3 + 1], sz = scales[g * 3 + 2];
        int vx = (int)floorf((mx - PCMINX) / GRIDSZ);
        int vy = (int)floorf((my - PCMINY) / GRIDSZ);
        float smax = fmaxf(sx, fmaxf(sy, sz));
        int rad = (int)ceilf(smax * SCALE_MULTC / GRIDSZ);
        if (rad < 1) rad = 1;
        // arithmetic >> floors negatives
        bool ov = (((vx - rad) >> TSH) <= tx) & (((vx + rad) >> TSH) >= tx) &
                  (((vy - rad) >> TSH) <= ty) & (((vy + rad) >> TSH) >= ty);
        unsigned long long bal = __ballot(ov);
        if (ov) {
            int pos = (int)cl + (int)__popcll(bal & ((1ull << lane) - 1ull));
            if (pos < SEGC) candSeg[w][pos] = (unsigned short)g;
        }
        cl += (unsigned)__popcll(bal);
    }
    if (lane == 0) wc[w] = min((int)cl, SEGC);
    __syncthreads();

    const int c0 = wc[0], c1 = wc[1], c2 = wc[2], c3 = wc[3];
    const int o1 = c0, o2 = o1 + c1, o3 = o2 + c2;
    const int total = o3 + c3;   // <= 128

    if (tid < total) {
        int s, idx;
        if (tid < o1)      { s = 0; idx = tid; }
        else if (tid < o2) { s = 1; idx = tid - o1; }
        else if (tid < o3) { s = 2; idx = tid - o2; }
        else               { s = 3; idx = tid - o3; }
        int g = (int)candSeg[s][idx];
        float mx = means3D[g * 3 + 0], my = means3D[g * 3 + 1], mz = means3D[g * 3 + 2];
        float sx = scales[g * 3 + 0], sy = scales[g * 3 + 1], sz = scales[g * 3 + 2];
        float r[9];
#pragma unroll
        for (int i = 0; i < 9; ++i) r[i] = rot3D[g * 9 + i];
        float sem[NC];
#pragma unroll
        for (int c = 0; c < NC; ++c) sem[c] = semantics[(size_t)g * NC + c];
        float ug = uu[g], vg = vv[g], op = opas[g];
        int vx = (int)floorf((mx - PCMINX) / GRIDSZ);
        int vy = (int)floorf((my - PCMINY) / GRIDSZ);
        int vz = (int)floorf((mz - PCMINZ) / GRIDSZ);
        float smax = fmaxf(sx, fmaxf(sy, sz));
        int rad = (int)ceilf(smax * SCALE_MULTC / GRIDSZ);
        if (rad < 1) rad = 1;

        float4* Rv = (float4*)(rowTbl + ((size_t)b * CCAP + tid) * ROWF);
        Rv[0] = make_float4(mx * r[0] + my * r[3] + mz * r[6],
                            mx * r[1] + my * r[4] + mz * r[7],
                            mx * r[2] + my * r[5] + mz * r[8], r[0]);
        Rv[1] = make_float4(r[1], r[2], r[3], r[4]);
        Rv[2] = make_float4(r[5], r[6], r[7], r[8]);
        Rv[3] = make_float4(1.0f / sx, 1.0f / sy, 1.0f / sz, op);
        Rv[4] = make_float4(1.0f / ug, 1.0f / vg, vg / ug, sem[16]);
        Rv[5] = make_float4(sem[0], sem[1], sem[2], sem[3]);
        Rv[6] = make_float4(sem[4], sem[5], sem[6], sem[7]);
        Rv[7] = make_float4(sem[8], sem[9], sem[10], sem[11]);
        Rv[8] = make_float4(sem[12], sem[13], sem[14], sem[15]);
        Rv[9] = make_float4(__int_as_float(vx), __int_as_float(vy),
                            __int_as_float(vz), __int_as_float(rad));
    }
    if (tid == 0) candCnt[b] = (unsigned)total;
}

__device__ __forceinline__ float eval_row(const float* __restrict__ R,
                                          float px, float py, float pz,
                                          int ix, int iy, int iz) {
    const float4* Rv = (const float4*)R;
    float4 f0 = Rv[0], f1 = Rv[1], f2 = Rv[2], f3 = Rv[3], f4 = Rv[4], f9 = Rv[9];
    int cheb = max(max(abs(ix - __float_as_int(f9.x)),
                       abs(iy - __float_as_int(f9.y))),
                   abs(iz - __float_as_int(f9.z)));
    float l0 = px * f0.w + py * f1.z + pz * f2.y - f0.x;
    float l1 = px * f1.x + py * f1.w + pz * f2.z - f0.y;
    float l2 = px * f1.y + py * f2.x + pz * f2.w - f0.z;
    float t0 = l0 * f3.x, t1 = l1 * f3.y, t2 = l2 * f3.z;
    float s0 = t0 * t0 + 1e-8f;
    float s1 = t1 * t1 + 1e-8f;
    float s2 = t2 * t2 + 1e-8f;
    float f = __powf(__powf(s0, f4.y) + __powf(s1, f4.y), f4.z) + __powf(s2, f4.x);
    float a = f3.w * __expf(-0.5f * f);
    return (cheb <= __float_as_int(f9.w)) ? a : 0.0f;
}

// Dispatch 2: 4 POINTS PER WAVE. lane = (sub, k): sub = lane>>4 selects the
// point, k = lane&15 the candidate slot. n = candCnt[tile] is uniform within
// each 16-lane group. Per pass j: slot lane evaluates candidate 16j+k
// (predicated, a=0 contributes 0 to everything), then in-pass matvec:
// broadcast a within the group via shfl, lane k = channel k (k==0 also does
// channel 16), semantics read from the staged rows in ascending-candidate
// order => deterministic. dens/lb: 4-level shfl_xor group reduce.
__global__ __launch_bounds__(256)
void point_kernel(const float* __restrict__ pts,
                  const unsigned int* __restrict__ candCnt,
                  const float* __restrict__ rowTbl,
                  float* __restrict__ out) {
    const int tid = threadIdx.x;
    const int lane = tid & 63;
    const int w = tid >> 6;
    const int sub = lane >> 4;        // point within wave (0..3)
    const int k = lane & 15;          // candidate slot / channel
    const int p = blockIdx.x * 16 + w * 4 + sub;

    float px = pts[p * 3 + 0], py = pts[p * 3 + 1], pz = pts[p * 3 + 2];
    int ix = (int)floorf((px - PCMINX) / GRIDSZ);
    int iy = (int)floorf((py - PCMINY) / GRIDSZ);
    int iz = (int)floorf((pz - PCMINZ) / GRIDSZ);
    int t = (iy >> TSH) * NTX + (ix >> TSH);
    int n = (int)candCnt[t];          // uniform within the 16-lane group
    const float* base = rowTbl + (size_t)t * CCAP * ROWF;

    float dens = 0.0f, lb = 0.0f, acc = 0.0f, acc16 = 0.0f;

    for (int j = 0; j * 16 < n; ++j) {
        int kk = j * 16 + k;
        float a = 0.0f;
        if (kk < n)
            a = eval_row(base + (size_t)kk * ROWF, px, py, pz, ix, iy, iz);
        dens += a;
        lb += __logf(1.0f - fminf(a, 1.0f - 1e-4f));   // a=0 -> 0

        int kmax = min(16, n - j * 16);
        for (int kq = 0; kq < kmax; ++kq) {
            float aq = __shfl(a, (sub << 4) + kq);
            const float* R = base + (size_t)(j * 16 + kq) * ROWF;
            acc = fmaf(aq, R[20 + k], acc);            // channel k (0..15)
            if (k == 0) acc16 = fmaf(aq, R[19], acc16); // channel 16
        }
    }

#pragma unroll
    for (int o = 1; o < 16; o <<= 1) {
        dens += __shfl_xor(dens, o);
        lb += __shfl_xor(lb, o);
    }

    float inv = 1.0f / (dens + 1e-9f);
    out[(size_t)p * NC + k] = acc * inv;               // channels 0..15
    if (k == 0) {
        out[(size_t)p * NC + 16] = acc16 * inv;
        out[(size_t)NP * NC + p] = 1.0f - expf(lb);
        out[(size_t)NP * NC + NP + p] = dens;
    }
}

// ---- fallback (ws too small): monolithic kernel ----
__global__ __launch_bounds__(64)
void agg_kernel_fb(const float* __restrict__ pts,
                   const float* __restrict__ means3D,
                   const float* __restrict__ opas,
                   const float* __restrict__ uu,
                   const float* __restrict__ vv,
                   const float* __restrict__ semantics,
                   const float* __restrict__ scales,
                   const float* __restrict__ rot3D,
                   float* __restrict__ out) {
    int p = blockIdx.x * 64 + threadIdx.x;
    if (p >= NP) return;
    float px = pts[p * 3 + 0], py = pts[p * 3 + 1], pz = pts[p * 3 + 2];
    int pix = (int)floorf((px - PCMINX) / GRIDSZ);
    int piy = (int)floorf((py - PCMINY) / GRIDSZ);
    int piz = (int)floorf((pz - PCMINZ) / GRIDSZ);
    float density = 0.0f, logbin = 0.0f;
    float acc[NC];
#pragma unroll
    for (int c = 0; c < NC; ++c) acc[c] = 0.0f;
    for (int g = 0; g < NG; ++g) {
        float mx = means3D[g * 3 + 0], my = means3D[g * 3 + 1], mz = means3D[g * 3 + 2];
        float sx = scales[g * 3 + 0], sy = scales[g * 3 + 1], sz = scales[g * 3 + 2];
        int vx = (int)floorf((mx - PCMINX) / GRIDSZ);
        int vy = (int)floorf((my - PCMINY) / GRIDSZ);
        int vz = (int)floorf((mz - PCMINZ) / GRIDSZ);
        float smax = fmaxf(sx, fmaxf(sy, sz));
        int rad = (int)ceilf(smax * SCALE_MULTC / GRIDSZ);
        rad = rad < 1 ? 1 : rad;
        int cheb = max(abs(pix - vx), max(abs(piy - vy), abs(piz - vz)));
        if (cheb <= rad) {
            const float* r = rot3D + (size_t)g * 9;
            float dx = px - mx, dy = py - my, dz = pz - mz;
            float l0 = dx * r[0] + dy * r[3] + dz * r[6];
            float l1 = dx * r[1] + dy * r[4] + dz * r[7];
            float l2 = dx * r[2] + dy * r[5] + dz * r[8];
            float t0 = l0 / sx, t1 = l1 / sy, t2 = l2 / sz;
            float s0 = t0 * t0 + 1e-8f, s1 = t1 * t1 + 1e-8f, s2 = t2 * t2 + 1e-8f;
            float ie1 = 1.0f / uu[g], ie2 = 1.0f / vv[g], e21 = vv[g] * ie1;
            float f = __powf(__powf(s0, ie2) + __powf(s1, ie2), e21) + __powf(s2, ie1);
            float a = opas[g] * __expf(-0.5f * f);
            density += a;
            const float* sg = semantics + (size_t)g * NC;
#pragma unroll
            for (int c = 0; c < NC; ++c) acc[c] = fmaf(a, sg[c], acc[c]);
            logbin += __logf(1.0f - fminf(a, 1.0f - 1e-4f));
        }
    }
    float inv = 1.0f / (density + 1e-9f);
#pragma unroll
    for (int c = 0; c < NC; ++c) out[(size_t)p * NC + c] = acc[c] * inv;
    out[(size_t)NP * NC + p] = 1.0f - expf(logbin);
    out[(size_t)NP * NC + NP + p] = density;
}

extern "C" void kernel_launch(void* const* d_in, const int* in_sizes, int n_in,
                              void* d_out, int out_size, void* d_ws, size_t ws_size,
                              hipStream_t stream) {
    const float* pts       = (const float*)d_in[0];
    const float* means3D   = (const float*)d_in[1];
    const float* opas      = (const float*)d_in[2];
    const float* uu        = (const float*)d_in[3];
    const float* vv        = (const float*)d_in[4];
    const float* semantics = (const float*)d_in[5];
    const float* scales    = (const float*)d_in[6];
    const float* rot3D     = (const float*)d_in[7];
    float* out = (float*)d_out;

    size_t cntBytes = ((size_t)NTILE * sizeof(unsigned int) + 255) & ~(size_t)255; // 2.6 KB
    size_t rowBytes = (size_t)NTILE * CCAP * ROWF * sizeof(float);                 // 12.8 MB
    size_t need = cntBytes + rowBytes;

    if (ws_size >= need) {
        unsigned int* candCnt = (unsigned int*)d_ws;
        float* rowTbl = (float*)((char*)d_ws + cntBytes);
        bin_kernel<<<NTILE, 256, 0, stream>>>(means3D, opas, uu, vv, semantics,
                                              scales, rot3D, candCnt, rowTbl);
        point_kernel<<<NP / 16, 256, 0, stream>>>(pts, candCnt, rowTbl, out);
    } else {
        agg_kernel_fb<<<NP / 64, 64, 0, stream>>>(pts, means3D, opas, uu, vv, semantics,
                                                  scales, rot3D, out);
    }
}

// Round 17
// 28.153 us; speedup vs baseline: 3.3542x; 1.0416x over previous
//
#include <hip/hip_runtime.h>
#include <math.h>

#define NP 16384
#define NG 2048
#define NC 17

#define TSH 3            // tile = 8x8 voxels in (x,y)
#define NTX 25
#define NTY 25
#define NTILE (NTX * NTY)   // 625
#define SEGC 32          // per-wave candidate cap in bin (4 ranges of 512 prims)
#define CCAP 128         // per-tile candidate cap (mean ~13), multiple of 16
#define ROWF 40          // floats per candidate row

#define GRIDSZ 0.4f
#define PCMINX -40.0f
#define PCMINY -40.0f
#define PCMINZ -1.0f
#define SCALE_MULTC 3.0f

// Row layout (40 floats, 10 float4s):
// f0={mur0,mur1,mur2,r0} f1={r1,r2,r3,r4} f2={r5,r6,r8,r8} f3={1/sx,1/sy,1/sz,opa}
// f4={1/u,1/v,v/u,sem16} f5..f8=sem[0..15] f9={vx,vy,vz,rad}(ints)
// Channel c<16 at float 20+c; channel 16 at float 19.
// Zero rows are inert: opa=0 => a=0 => no contribution (powf(x,0)=1 is finite).

// Dispatch 1: one block per tile; ballot-compact overlapping prims (ascending
// g, deterministic, no atomics, no memset); thread i builds candidate row i;
// rows padded with zeros to a multiple of 16; candCnt = padded count.
__global__ __launch_bounds__(256)
void bin_kernel(const float* __restrict__ means3D, const float* __restrict__ opas,
                const float* __restrict__ uu, const float* __restrict__ vv,
                const float* __restrict__ semantics, const float* __restrict__ scales,
                const float* __restrict__ rot3D,
                unsigned int* __restrict__ candCnt, float* __restrict__ rowTbl) {
    __shared__ unsigned short candSeg[4][SEGC];
    __shared__ int wc[4];
    const int tid = threadIdx.x;
    const int lane = tid & 63;
    const int w = tid >> 6;
    const int b = blockIdx.x;
    const int tx = b % NTX, ty = b / NTX;

    // de-serialized scan: all loads/tests first (independent), then compact
    bool ov[8];
#pragma unroll
    for (int it = 0; it < 8; ++it) {
        int g = w * 512 + it * 64 + lane;
        float mx = means3D[g * 3 + 0], my = means3D[g * 3 + 1];
        float sx = scales[g * 3 + 0], sy = scales[g * 3 + 1], sz = scales[g * 3 + 2];
        int vx = (int)floorf((mx - PCMINX) / GRIDSZ);
        int vy = (int)floorf((my - PCMINY) / GRIDSZ);
        float smax = fmaxf(sx, fmaxf(sy, sz));
        int rad = (int)ceilf(smax * SCALE_MULTC / GRIDSZ);
        if (rad < 1) rad = 1;
        // arithmetic >> floors negatives
        ov[it] = (((vx - rad) >> TSH) <= tx) & (((vx + rad) >> TSH) >= tx) &
                 (((vy - rad) >> TSH) <= ty) & (((vy + rad) >> TSH) >= ty);
    }
    unsigned cl = 0;
#pragma unroll
    for (int it = 0; it < 8; ++it) {
        unsigned long long bal = __ballot(ov[it]);
        if (ov[it]) {
            int pos = (int)cl + (int)__popcll(bal & ((1ull << lane) - 1ull));
            if (pos < SEGC) candSeg[w][pos] = (unsigned short)(w * 512 + it * 64 + lane);
        }
        cl += (unsigned)__popcll(bal);
    }
    if (lane == 0) wc[w] = min((int)cl, SEGC);
    __syncthreads();

    const int c0 = wc[0], c1 = wc[1], c2 = wc[2], c3 = wc[3];
    const int o1 = c0, o2 = o1 + c1, o3 = o2 + c2;
    const int total = o3 + c3;                 // <= 128
    const int pad = (total + 15) & ~15;        // <= 128

    if (tid < total) {
        int s, idx;
        if (tid < o1)      { s = 0; idx = tid; }
        else if (tid < o2) { s = 1; idx = tid - o1; }
        else if (tid < o3) { s = 2; idx = tid - o2; }
        else               { s = 3; idx = tid - o3; }
        int g = (int)candSeg[s][idx];
        float mx = means3D[g * 3 + 0], my = means3D[g * 3 + 1], mz = means3D[g * 3 + 2];
        float sx = scales[g * 3 + 0], sy = scales[g * 3 + 1], sz = scales[g * 3 + 2];
        float r[9];
#pragma unroll
        for (int i = 0; i < 9; ++i) r[i] = rot3D[g * 9 + i];
        float sem[NC];
#pragma unroll
        for (int c = 0; c < NC; ++c) sem[c] = semantics[(size_t)g * NC + c];
        float ug = uu[g], vg = vv[g], op = opas[g];
        int vx = (int)floorf((mx - PCMINX) / GRIDSZ);
        int vy = (int)floorf((my - PCMINY) / GRIDSZ);
        int vz = (int)floorf((mz - PCMINZ) / GRIDSZ);
        float smax = fmaxf(sx, fmaxf(sy, sz));
        int rad = (int)ceilf(smax * SCALE_MULTC / GRIDSZ);
        if (rad < 1) rad = 1;

        float4* Rv = (float4*)(rowTbl + ((size_t)b * CCAP + tid) * ROWF);
        Rv[0] = make_float4(mx * r[0] + my * r[3] + mz * r[6],
                            mx * r[1] + my * r[4] + mz * r[7],
                            mx * r[2] + my * r[5] + mz * r[8], r[0]);
        Rv[1] = make_float4(r[1], r[2], r[3], r[4]);
        Rv[2] = make_float4(r[5], r[6], r[7], r[8]);
        Rv[3] = make_float4(1.0f / sx, 1.0f / sy, 1.0f / sz, op);
        Rv[4] = make_float4(1.0f / ug, 1.0f / vg, vg / ug, sem[16]);
        Rv[5] = make_float4(sem[0], sem[1], sem[2], sem[3]);
        Rv[6] = make_float4(sem[4], sem[5], sem[6], sem[7]);
        Rv[7] = make_float4(sem[8], sem[9], sem[10], sem[11]);
        Rv[8] = make_float4(sem[12], sem[13], sem[14], sem[15]);
        Rv[9] = make_float4(__int_as_float(vx), __int_as_float(vy),
                            __int_as_float(vz), __int_as_float(rad));
    } else if (tid < pad) {
        // inert zero row
        float4* Rv = (float4*)(rowTbl + ((size_t)b * CCAP + tid) * ROWF);
        float4 z = make_float4(0.0f, 0.0f, 0.0f, 0.0f);
#pragma unroll
        for (int i = 0; i < 10; ++i) Rv[i] = z;
    }
    if (tid == 0) candCnt[b] = (unsigned)pad;
}

__device__ __forceinline__ float eval_row(const float* __restrict__ R,
                                          float px, float py, float pz,
                                          int ix, int iy, int iz) {
    const float4* Rv = (const float4*)R;
    float4 f0 = Rv[0], f1 = Rv[1], f2 = Rv[2], f3 = Rv[3], f4 = Rv[4], f9 = Rv[9];
    int cheb = max(max(abs(ix - __float_as_int(f9.x)),
                       abs(iy - __float_as_int(f9.y))),
                   abs(iz - __float_as_int(f9.z)));
    float l0 = px * f0.w + py * f1.z + pz * f2.y - f0.x;
    float l1 = px * f1.x + py * f1.w + pz * f2.z - f0.y;
    float l2 = px * f1.y + py * f2.x + pz * f2.w - f0.z;
    float t0 = l0 * f3.x, t1 = l1 * f3.y, t2 = l2 * f3.z;
    float s0 = t0 * t0 + 1e-8f;
    float s1 = t1 * t1 + 1e-8f;
    float s2 = t2 * t2 + 1e-8f;
    float f = __powf(__powf(s0, f4.y) + __powf(s1, f4.y), f4.z) + __powf(s2, f4.x);
    float a = f3.w * __expf(-0.5f * f);
    return (cheb <= __float_as_int(f9.w)) ? a : 0.0f;
}

// Dispatch 2: 4 points per wave; lane = (sub=point, k=candidate slot/channel).
// n is padded to a multiple of 16 => every loop has fixed trip counts, no
// gates; pad rows are inert. Product form replaces log-sum for bin_logits.
// Fully deterministic (fixed orders everywhere).
__global__ __launch_bounds__(256)
void point_kernel(const float* __restrict__ pts,
                  const unsigned int* __restrict__ candCnt,
                  const float* __restrict__ rowTbl,
                  float* __restrict__ out) {
    const int tid = threadIdx.x;
    const int lane = tid & 63;
    const int w = tid >> 6;
    const int sub = lane >> 4;        // point within wave (0..3)
    const int k = lane & 15;          // candidate slot / channel
    const int p = blockIdx.x * 16 + w * 4 + sub;

    float px = pts[p * 3 + 0], py = pts[p * 3 + 1], pz = pts[p * 3 + 2];
    int ix = (int)floorf((px - PCMINX) / GRIDSZ);
    int iy = (int)floorf((py - PCMINY) / GRIDSZ);
    int iz = (int)floorf((pz - PCMINZ) / GRIDSZ);
    int t = (iy >> TSH) * NTX + (ix >> TSH);
    int n = (int)candCnt[t];          // padded multiple of 16, uniform in group
    const float* base = rowTbl + (size_t)t * CCAP * ROWF;

    float dens = 0.0f, prod = 1.0f, acc = 0.0f, acc16 = 0.0f;

    for (int j = 0; j < n; j += 16) {
        float a = eval_row(base + (size_t)(j + k) * ROWF, px, py, pz, ix, iy, iz);
        dens += a;
        prod *= 1.0f - fminf(a, 1.0f - 1e-4f);

#pragma unroll
        for (int kq = 0; kq < 16; ++kq) {
            float aq = __shfl(a, (sub << 4) + kq);
            const float* R = base + (size_t)(j + kq) * ROWF;
            acc = fmaf(aq, R[20 + k], acc);             // channel k (0..15)
            if (k == 0) acc16 = fmaf(aq, R[19], acc16); // channel 16
        }
    }

#pragma unroll
    for (int o = 1; o < 16; o <<= 1) {
        dens += __shfl_xor(dens, o);
        prod *= __shfl_xor(prod, o);
    }

    float inv = 1.0f / (dens + 1e-9f);
    out[(size_t)p * NC + k] = acc * inv;                // channels 0..15
    if (k == 0) {
        out[(size_t)p * NC + 16] = acc16 * inv;
        out[(size_t)NP * NC + p] = 1.0f - prod;
        out[(size_t)NP * NC + NP + p] = dens;
    }
}

// ---- fallback (ws too small): monolithic kernel ----
__global__ __launch_bounds__(64)
void agg_kernel_fb(const float* __restrict__ pts,
                   const float* __restrict__ means3D,
                   const float* __restrict__ opas,
                   const float* __restrict__ uu,
                   const float* __restrict__ vv,
                   const float* __restrict__ semantics,
                   const float* __restrict__ scales,
                   const float* __restrict__ rot3D,
                   float* __restrict__ out) {
    int p = blockIdx.x * 64 + threadIdx.x;
    if (p >= NP) return;
    float px = pts[p * 3 + 0], py = pts[p * 3 + 1], pz = pts[p * 3 + 2];
    int pix = (int)floorf((px - PCMINX) / GRIDSZ);
    int piy = (int)floorf((py - PCMINY) / GRIDSZ);
    int piz = (int)floorf((pz - PCMINZ) / GRIDSZ);
    float density = 0.0f, logbin = 0.0f;
    float acc[NC];
#pragma unroll
    for (int c = 0; c < NC; ++c) acc[c] = 0.0f;
    for (int g = 0; g < NG; ++g) {
        float mx = means3D[g * 3 + 0], my = means3D[g * 3 + 1], mz = means3D[g * 3 + 2];
        float sx = scales[g * 3 + 0], sy = scales[g * 3 + 1], sz = scales[g * 3 + 2];
        int vx = (int)floorf((mx - PCMINX) / GRIDSZ);
        int vy = (int)floorf((my - PCMINY) / GRIDSZ);
        int vz = (int)floorf((mz - PCMINZ) / GRIDSZ);
        float smax = fmaxf(sx, fmaxf(sy, sz));
        int rad = (int)ceilf(smax * SCALE_MULTC / GRIDSZ);
        rad = rad < 1 ? 1 : rad;
        int cheb = max(abs(pix - vx), max(abs(piy - vy), abs(piz - vz)));
        if (cheb <= rad) {
            const float* r = rot3D + (size_t)g * 9;
            float dx = px - mx, dy = py - my, dz = pz - mz;
            float l0 = dx * r[0] + dy * r[3] + dz * r[6];
            float l1 = dx * r[1] + dy * r[4] + dz * r[7];
            float l2 = dx * r[2] + dy * r[5] + dz * r[8];
            float t0 = l0 / sx, t1 = l1 / sy, t2 = l2 / sz;
            float s0 = t0 * t0 + 1e-8f, s1 = t1 * t1 + 1e-8f, s2 = t2 * t2 + 1e-8f;
            float ie1 = 1.0f / uu[g], ie2 = 1.0f / vv[g], e21 = vv[g] * ie1;
            float f = __powf(__powf(s0, ie2) + __powf(s1, ie2), e21) + __powf(s2, ie1);
            float a = opas[g] * __expf(-0.5f * f);
            density += a;
            const float* sg = semantics + (size_t)g * NC;
#pragma unroll
            for (int c = 0; c < NC; ++c) acc[c] = fmaf(a, sg[c], acc[c]);
            logbin += __logf(1.0f - fminf(a, 1.0f - 1e-4f));
        }
    }
    float inv = 1.0f / (density + 1e-9f);
#pragma unroll
    for (int c = 0; c < NC; ++c) out[(size_t)p * NC + c] = acc[c] * inv;
    out[(size_t)NP * NC + p] = 1.0f - expf(logbin);
    out[(size_t)NP * NC + NP + p] = density;
}

extern "C" void kernel_launch(void* const* d_in, const int* in_sizes, int n_in,
                              void* d_out, int out_size, void* d_ws, size_t ws_size,
                              hipStream_t stream) {
    const float* pts       = (const float*)d_in[0];
    const float* means3D   = (const float*)d_in[1];
    const float* opas      = (const float*)d_in[2];
    const float* uu        = (const float*)d_in[3];
    const float* vv        = (const float*)d_in[4];
    const float* semantics = (const float*)d_in[5];
    const float* scales    = (const float*)d_in[6];
    const float* rot3D     = (const float*)d_in[7];
    float* out = (float*)d_out;

    size_t cntBytes = ((size_t)NTILE * sizeof(unsigned int) + 255) & ~(size_t)255; // 2.6 KB
    size_t rowBytes = (size_t)NTILE * CCAP * ROWF * sizeof(float);                 // 12.8 MB
    size_t need = cntBytes + rowBytes;

    if (ws_size >= need) {
        unsigned int* candCnt = (unsigned int*)d_ws;
        float* rowTbl = (float*)((char*)d_ws + cntBytes);
        bin_kernel<<<NTILE, 256, 0, stream>>>(means3D, opas, uu, vv, semantics,
                                              scales, rot3D, candCnt, rowTbl);
        point_kernel<<<NP / 16, 256, 0, stream>>>(pts, candCnt, rowTbl, out);
    } else {
        agg_kernel_fb<<<NP / 64, 64, 0, stream>>>(pts, means3D, opas, uu, vv, semantics,
                                                  scales, rot3D, out);
    }
}

// Round 18
// 26.002 us; speedup vs baseline: 3.6316x; 1.0827x over previous
//
#include <hip/hip_runtime.h>
#include <math.h>

#define NP 16384
#define NG 2048
#define NC 17

#define TSH 3            // tile = 8x8 voxels in (x,y)
#define NTX 25
#define NTY 25
#define NTILE (NTX * NTY)   // 625
#define SEGC 32          // per-wave candidate cap in bin (4 ranges of 512 prims)
#define CCAP 128         // per-tile candidate cap (mean ~13), multiple of 16
#define ROWF 40          // floats per candidate row

#define GRIDSZ 0.4f
#define PCMINX -40.0f
#define PCMINY -40.0f
#define PCMINZ -1.0f
#define SCALE_MULTC 3.0f

// Row layout (40 floats, 10 float4s):
// f0={mur0,mur1,mur2,r0} f1={r1,r2,r3,r4} f2={r5,r6,r7,r8} f3={1/sx,1/sy,1/sz,opa}
// f4={1/u,1/v,v/u,sem16} f5..f8=sem[0..15] f9={vx,vy,vz,rad}(ints)
// Channel c<16 at float 20+c; channel 16 at float 19.
// Zero rows are inert: opa=0 => a=0 => no contribution.

// Dispatch 1: one block per tile; ballot-compact overlapping prims (ascending
// g, deterministic, no atomics, no memset); thread i builds candidate row i;
// rows padded with zeros to a multiple of 16; candCnt = padded count.
__global__ __launch_bounds__(256)
void bin_kernel(const float* __restrict__ means3D, const float* __restrict__ opas,
                const float* __restrict__ uu, const float* __restrict__ vv,
                const float* __restrict__ semantics, const float* __restrict__ scales,
                const float* __restrict__ rot3D,
                unsigned int* __restrict__ candCnt, float* __restrict__ rowTbl) {
    __shared__ unsigned short candSeg[4][SEGC];
    __shared__ int wc[4];
    const int tid = threadIdx.x;
    const int lane = tid & 63;
    const int w = tid >> 6;
    const int b = blockIdx.x;
    const int tx = b % NTX, ty = b / NTX;

    // de-serialized scan: all loads/tests first (independent), then compact
    bool ov[8];
#pragma unroll
    for (int it = 0; it < 8; ++it) {
        int g = w * 512 + it * 64 + lane;
        float mx = means3D[g * 3 + 0], my = means3D[g * 3 + 1];
        float sx = scales[g * 3 + 0], sy = scales[g * 3 + 1], sz = scales[g * 3 + 2];
        int vx = (int)floorf((mx - PCMINX) / GRIDSZ);
        int vy = (int)floorf((my - PCMINY) / GRIDSZ);
        float smax = fmaxf(sx, fmaxf(sy, sz));
        int rad = (int)ceilf(smax * SCALE_MULTC / GRIDSZ);
        if (rad < 1) rad = 1;
        // arithmetic >> floors negatives
        ov[it] = (((vx - rad) >> TSH) <= tx) & (((vx + rad) >> TSH) >= tx) &
                 (((vy - rad) >> TSH) <= ty) & (((vy + rad) >> TSH) >= ty);
    }
    unsigned cl = 0;
#pragma unroll
    for (int it = 0; it < 8; ++it) {
        unsigned long long bal = __ballot(ov[it]);
        if (ov[it]) {
            int pos = (int)cl + (int)__popcll(bal & ((1ull << lane) - 1ull));
            if (pos < SEGC) candSeg[w][pos] = (unsigned short)(w * 512 + it * 64 + lane);
        }
        cl += (unsigned)__popcll(bal);
    }
    if (lane == 0) wc[w] = min((int)cl, SEGC);
    __syncthreads();

    const int c0 = wc[0], c1 = wc[1], c2 = wc[2], c3 = wc[3];
    const int o1 = c0, o2 = o1 + c1, o3 = o2 + c2;
    const int total = o3 + c3;                 // <= 128
    const int pad = (total + 15) & ~15;        // <= 128

    if (tid < total) {
        int s, idx;
        if (tid < o1)      { s = 0; idx = tid; }
        else if (tid < o2) { s = 1; idx = tid - o1; }
        else if (tid < o3) { s = 2; idx = tid - o2; }
        else               { s = 3; idx = tid - o3; }
        int g = (int)candSeg[s][idx];
        float mx = means3D[g * 3 + 0], my = means3D[g * 3 + 1], mz = means3D[g * 3 + 2];
        float sx = scales[g * 3 + 0], sy = scales[g * 3 + 1], sz = scales[g * 3 + 2];
        float r[9];
#pragma unroll
        for (int i = 0; i < 9; ++i) r[i] = rot3D[g * 9 + i];
        float sem[NC];
#pragma unroll
        for (int c = 0; c < NC; ++c) sem[c] = semantics[(size_t)g * NC + c];
        float ug = uu[g], vg = vv[g], op = opas[g];
        int vx = (int)floorf((mx - PCMINX) / GRIDSZ);
        int vy = (int)floorf((my - PCMINY) / GRIDSZ);
        int vz = (int)floorf((mz - PCMINZ) / GRIDSZ);
        float smax = fmaxf(sx, fmaxf(sy, sz));
        int rad = (int)ceilf(smax * SCALE_MULTC / GRIDSZ);
        if (rad < 1) rad = 1;

        float4* Rv = (float4*)(rowTbl + ((size_t)b * CCAP + tid) * ROWF);
        Rv[0] = make_float4(mx * r[0] + my * r[3] + mz * r[6],
                            mx * r[1] + my * r[4] + mz * r[7],
                            mx * r[2] + my * r[5] + mz * r[8], r[0]);
        Rv[1] = make_float4(r[1], r[2], r[3], r[4]);
        Rv[2] = make_float4(r[5], r[6], r[7], r[8]);
        Rv[3] = make_float4(1.0f / sx, 1.0f / sy, 1.0f / sz, op);
        Rv[4] = make_float4(1.0f / ug, 1.0f / vg, vg / ug, sem[16]);
        Rv[5] = make_float4(sem[0], sem[1], sem[2], sem[3]);
        Rv[6] = make_float4(sem[4], sem[5], sem[6], sem[7]);
        Rv[7] = make_float4(sem[8], sem[9], sem[10], sem[11]);
        Rv[8] = make_float4(sem[12], sem[13], sem[14], sem[15]);
        Rv[9] = make_float4(__int_as_float(vx), __int_as_float(vy),
                            __int_as_float(vz), __int_as_float(rad));
    } else if (tid < pad) {
        // inert zero row
        float4* Rv = (float4*)(rowTbl + ((size_t)b * CCAP + tid) * ROWF);
        float4 z = make_float4(0.0f, 0.0f, 0.0f, 0.0f);
#pragma unroll
        for (int i = 0; i < 10; ++i) Rv[i] = z;
    }
    if (tid == 0) candCnt[b] = (unsigned)pad;
}

__device__ __forceinline__ float eval_row(const float* __restrict__ R,
                                          float px, float py, float pz,
                                          int ix, int iy, int iz) {
    const float4* Rv = (const float4*)R;
    float4 f0 = Rv[0], f1 = Rv[1], f2 = Rv[2], f3 = Rv[3], f4 = Rv[4], f9 = Rv[9];
    int cheb = max(max(abs(ix - __float_as_int(f9.x)),
                       abs(iy - __float_as_int(f9.y))),
                   abs(iz - __float_as_int(f9.z)));
    float l0 = px * f0.w + py * f1.z + pz * f2.y - f0.x;
    float l1 = px * f1.x + py * f1.w + pz * f2.z - f0.y;
    float l2 = px * f1.y + py * f2.x + pz * f2.w - f0.z;
    float t0 = l0 * f3.x, t1 = l1 * f3.y, t2 = l2 * f3.z;
    float s0 = t0 * t0 + 1e-8f;
    float s1 = t1 * t1 + 1e-8f;
    float s2 = t2 * t2 + 1e-8f;
    float f = __powf(__powf(s0, f4.y) + __powf(s1, f4.y), f4.z) + __powf(s2, f4.x);
    float a = f3.w * __expf(-0.5f * f);
    return (cheb <= __float_as_int(f9.w)) ? a : 0.0f;
}

// Dispatch 2: 4 points per wave; lane = (sub=point, k=candidate slot/channel).
// n padded to multiple of 16 => fixed trip counts. Per pass: evaluate slot
// candidate, then ILP-exposed matvec: ALL 16 bpermute broadcasts issued
// back-to-back (independent), ALL 16(+16) weight loads issued back-to-back
// (independent), then the pure-fmaf reduce chain. Bit-identical result to the
// serial form; fully deterministic.
__global__ __launch_bounds__(256)
void point_kernel(const float* __restrict__ pts,
                  const unsigned int* __restrict__ candCnt,
                  const float* __restrict__ rowTbl,
                  float* __restrict__ out) {
    const int tid = threadIdx.x;
    const int lane = tid & 63;
    const int w = tid >> 6;
    const int sub = lane >> 4;        // point within wave (0..3)
    const int k = lane & 15;          // candidate slot / channel
    const int p = blockIdx.x * 16 + w * 4 + sub;

    float px = pts[p * 3 + 0], py = pts[p * 3 + 1], pz = pts[p * 3 + 2];
    int ix = (int)floorf((px - PCMINX) / GRIDSZ);
    int iy = (int)floorf((py - PCMINY) / GRIDSZ);
    int iz = (int)floorf((pz - PCMINZ) / GRIDSZ);
    int t = (iy >> TSH) * NTX + (ix >> TSH);
    int n = (int)candCnt[t];          // padded multiple of 16, uniform in group
    const float* base = rowTbl + (size_t)t * CCAP * ROWF;

    float dens = 0.0f, prod = 1.0f, acc = 0.0f, acc16 = 0.0f;

    for (int j = 0; j < n; j += 16) {
        float a = eval_row(base + (size_t)(j + k) * ROWF, px, py, pz, ix, iy, iz);
        dens += a;
        prod *= 1.0f - fminf(a, 1.0f - 1e-4f);

        // --- batched broadcasts: 16 independent bpermutes, issued together ---
        float aq[16];
#pragma unroll
        for (int kq = 0; kq < 16; ++kq)
            aq[kq] = __shfl(a, (sub << 4) + kq);

        // --- batched weight loads: independent addresses, issued together ---
        float wt[16];
#pragma unroll
        for (int kq = 0; kq < 16; ++kq)
            wt[kq] = base[(size_t)(j + kq) * ROWF + 20 + k];

        float wt16[16];
        if (k == 0) {
#pragma unroll
            for (int kq = 0; kq < 16; ++kq)
                wt16[kq] = base[(size_t)(j + kq) * ROWF + 19];
        }

        // --- pure-fmaf reduce chains ---
#pragma unroll
        for (int kq = 0; kq < 16; ++kq)
            acc = fmaf(aq[kq], wt[kq], acc);            // channel k (0..15)
        if (k == 0) {
#pragma unroll
            for (int kq = 0; kq < 16; ++kq)
                acc16 = fmaf(aq[kq], wt16[kq], acc16);  // channel 16
        }
    }

#pragma unroll
    for (int o = 1; o < 16; o <<= 1) {
        dens += __shfl_xor(dens, o);
        prod *= __shfl_xor(prod, o);
    }

    float inv = 1.0f / (dens + 1e-9f);
    out[(size_t)p * NC + k] = acc * inv;                // channels 0..15
    if (k == 0) {
        out[(size_t)p * NC + 16] = acc16 * inv;
        out[(size_t)NP * NC + p] = 1.0f - prod;
        out[(size_t)NP * NC + NP + p] = dens;
    }
}

// ---- fallback (ws too small): monolithic kernel ----
__global__ __launch_bounds__(64)
void agg_kernel_fb(const float* __restrict__ pts,
                   const float* __restrict__ means3D,
                   const float* __restrict__ opas,
                   const float* __restrict__ uu,
                   const float* __restrict__ vv,
                   const float* __restrict__ semantics,
                   const float* __restrict__ scales,
                   const float* __restrict__ rot3D,
                   float* __restrict__ out) {
    int p = blockIdx.x * 64 + threadIdx.x;
    if (p >= NP) return;
    float px = pts[p * 3 + 0], py = pts[p * 3 + 1], pz = pts[p * 3 + 2];
    int pix = (int)floorf((px - PCMINX) / GRIDSZ);
    int piy = (int)floorf((py - PCMINY) / GRIDSZ);
    int piz = (int)floorf((pz - PCMINZ) / GRIDSZ);
    float density = 0.0f, logbin = 0.0f;
    float acc[NC];
#pragma unroll
    for (int c = 0; c < NC; ++c) acc[c] = 0.0f;
    for (int g = 0; g < NG; ++g) {
        float mx = means3D[g * 3 + 0], my = means3D[g * 3 + 1], mz = means3D[g * 3 + 2];
        float sx = scales[g * 3 + 0], sy = scales[g * 3 + 1], sz = scales[g * 3 + 2];
        int vx = (int)floorf((mx - PCMINX) / GRIDSZ);
        int vy = (int)floorf((my - PCMINY) / GRIDSZ);
        int vz = (int)floorf((mz - PCMINZ) / GRIDSZ);
        float smax = fmaxf(sx, fmaxf(sy, sz));
        int rad = (int)ceilf(smax * SCALE_MULTC / GRIDSZ);
        rad = rad < 1 ? 1 : rad;
        int cheb = max(abs(pix - vx), max(abs(piy - vy), abs(piz - vz)));
        if (cheb <= rad) {
            const float* r = rot3D + (size_t)g * 9;
            float dx = px - mx, dy = py - my, dz = pz - mz;
            float l0 = dx * r[0] + dy * r[3] + dz * r[6];
            float l1 = dx * r[1] + dy * r[4] + dz * r[7];
            float l2 = dx * r[2] + dy * r[5] + dz * r[8];
            float t0 = l0 / sx, t1 = l1 / sy, t2 = l2 / sz;
            float s0 = t0 * t0 + 1e-8f, s1 = t1 * t1 + 1e-8f, s2 = t2 * t2 + 1e-8f;
            float ie1 = 1.0f / uu[g], ie2 = 1.0f / vv[g], e21 = vv[g] * ie1;
            float f = __powf(__powf(s0, ie2) + __powf(s1, ie2), e21) + __powf(s2, ie1);
            float a = opas[g] * __expf(-0.5f * f);
            density += a;
            const float* sg = semantics + (size_t)g * NC;
#pragma unroll
            for (int c = 0; c < NC; ++c) acc[c] = fmaf(a, sg[c], acc[c]);
            logbin += __logf(1.0f - fminf(a, 1.0f - 1e-4f));
        }
    }
    float inv = 1.0f / (density + 1e-9f);
#pragma unroll
    for (int c = 0; c < NC; ++c) out[(size_t)p * NC + c] = acc[c] * inv;
    out[(size_t)NP * NC + p] = 1.0f - expf(logbin);
    out[(size_t)NP * NC + NP + p] = density;
}

extern "C" void kernel_launch(void* const* d_in, const int* in_sizes, int n_in,
                              void* d_out, int out_size, void* d_ws, size_t ws_size,
                              hipStream_t stream) {
    const float* pts       = (const float*)d_in[0];
    const float* means3D   = (const float*)d_in[1];
    const float* opas      = (const float*)d_in[2];
    const float* uu        = (const float*)d_in[3];
    const float* vv        = (const float*)d_in[4];
    const float* semantics = (const float*)d_in[5];
    const float* scales    = (const float*)d_in[6];
    const float* rot3D     = (const float*)d_in[7];
    float* out = (float*)d_out;

    size_t cntBytes = ((size_t)NTILE * sizeof(unsigned int) + 255) & ~(size_t)255; // 2.6 KB
    size_t rowBytes = (size_t)NTILE * CCAP * ROWF * sizeof(float);                 // 12.8 MB
    size_t need = cntBytes + rowBytes;

    if (ws_size >= need) {
        unsigned int* candCnt = (unsigned int*)d_ws;
        float* rowTbl = (float*)((char*)d_ws + cntBytes);
        bin_kernel<<<NTILE, 256, 0, stream>>>(means3D, opas, uu, vv, semantics,
                                              scales, rot3D, candCnt, rowTbl);
        point_kernel<<<NP / 16, 256, 0, stream>>>(pts, candCnt, rowTbl, out);
    } else {
        agg_kernel_fb<<<NP / 64, 64, 0, stream>>>(pts, means3D, opas, uu, vv, semantics,
                                                  scales, rot3D, out);
    }
}